// Round 5
// baseline (597.212 us; speedup 1.0000x reference)
//
#include <hip/hip_runtime.h>

#define EDGES 32768
#define NODES 8192
#define PADMAX (EDGES + 4*128)   /* 33280: type segments padded to 128 rows */
#define MTILES (PADMAX/128)      /* 260 */

typedef unsigned short u16;
typedef __bf16 bf16x8 __attribute__((ext_vector_type(8)));
typedef float f32x4 __attribute__((ext_vector_type(4)));

#define MFMA16(a,b,c) __builtin_amdgcn_mfma_f32_16x16x32_bf16(a,b,c,0,0,0)
#define WAVE_LDS_FENCE() asm volatile("s_waitcnt lgkmcnt(0)" ::: "memory")

typedef __attribute__((address_space(1))) const unsigned int gas_u32;
typedef __attribute__((address_space(3))) unsigned int las_u32;
__device__ __forceinline__ void gl16(const void* g, void* l){
  __builtin_amdgcn_global_load_lds((gas_u32*)g, (las_u32*)l, 16, 0, 0);
}

__device__ __forceinline__ float b2f(u16 u){
  union{unsigned i; float f;} x; x.i = ((unsigned)u)<<16; return x.f;
}
__device__ __forceinline__ u16 f2b(float f){
  union{float f; unsigned i;} x; x.f = f;
  return (u16)((x.i + 0x7FFFu + ((x.i>>16)&1u)) >> 16);
}
__device__ __forceinline__ bf16x8 bzero(){
  bf16x8 z;
  #pragma unroll
  for (int i=0;i<8;i++) z[i] = (__bf16)0.0f;
  return z;
}
__device__ __forceinline__ void load8f(const float* p, float* v){
  *(float4*)(v)   = *(const float4*)(p);
  *(float4*)(v+4) = *(const float4*)(p+4);
}
__device__ __forceinline__ bf16x8 pack8(const float* v){
  bf16x8 r;
  #pragma unroll
  for (int j=0;j<8;j++) r[j] = (__bf16)v[j];
  return r;
}
// 16x32 bf16 LDS buffer, XOR-swizzled 8-elem chunks.
__device__ __forceinline__ int tadr(int c, int i){
  return c*32 + ((((i>>3) ^ ((c>>1)&3))&3)<<3) + (i&7);
}
// 4 chunk matrices (16x16 each)
__device__ __forceinline__ int cadr(int m, int cpr, int cc){
  return cc*64 + ((((m<<1) | (cpr>>3)) ^ (cc&7))<<3) + (cpr&7);
}

/* ---------------- sort by type (wave-aggregated atomics, G12) ---------------- */
__global__ void count_kernel(const int* __restrict__ eidx, const int* __restrict__ an,
                             int* __restrict__ wsi){
  int e = blockIdx.x*256 + threadIdx.x;
  int lane = threadIdx.x & 63;
  int t = an[eidx[e]] & 3;
  #pragma unroll
  for (int k = 0; k < 4; k++){
    unsigned long long m = __ballot(t == k);
    if (lane == k && m)
      atomicAdd(&wsi[k], __popcll(m));
  }
}
__global__ void scan_kernel(int* wsi){
  if (threadIdx.x == 0 && blockIdx.x == 0){
    int off = 0;
    for (int t = 0; t < 4; t++){
      wsi[8+t] = off;      // pad_off[t]
      wsi[4+t] = off;      // cursor[t]
      off += ((wsi[t] + 127) >> 7) << 7;
    }
    wsi[12] = off;         // pad_off[4] = total padded rows
  }
}
__global__ void scatter_kernel(const int* __restrict__ eidx, const int* __restrict__ an,
                               int* wsi, int* __restrict__ order){
  int e = blockIdx.x*256 + threadIdx.x;
  int lane = threadIdx.x & 63;
  int t = an[eidx[e]] & 3;
  unsigned long long lt = (1ull << lane) - 1ull;
  int pos = 0;
  #pragma unroll
  for (int k = 0; k < 4; k++){
    unsigned long long m = __ballot(t == k);      // convergent
    int bb = 0;
    if (lane == k && m) bb = atomicAdd(&wsi[4+k], __popcll(m));
    bb = __shfl(bb, k);                           // convergent broadcast
    if (t == k) pos = bb + __popcll(m & lt);
  }
  order[pos] = e;
}

/* ---------------- weight prep: fp32 (K,N) -> bf16 (N,K), optional row scale --- */
__global__ __launch_bounds__(256) void transpose_scale(
    const float* __restrict__ src, u16* __restrict__ dst, const float* __restrict__ gvec,
    int K, int Ncols){
  __shared__ u16 tile[64][65];
  int t = blockIdx.z;
  const float* S = src + (size_t)t*K*Ncols;
  u16* D = dst + (size_t)t*K*Ncols;
  int kb = blockIdx.y*64, nb = blockIdx.x*64;
  int tid = threadIdx.x;
  {
    int rr = tid >> 2, c0 = (tid & 3)*16;
    float g = gvec ? gvec[t*K + kb + rr] : 1.f;
    float v[16];
    load8f(S + (size_t)(kb+rr)*Ncols + nb + c0,     v);
    load8f(S + (size_t)(kb+rr)*Ncols + nb + c0 + 8, v+8);
    #pragma unroll
    for (int j=0;j<16;j++) tile[rr][c0+j] = f2b(v[j]*g);
  }
  __syncthreads();
  {
    int nr = tid >> 2, k0 = (tid & 3)*16;
    union{uint4 u; u16 h[8];} w0, w1;
    #pragma unroll
    for (int j=0;j<8;j++){ w0.h[j] = tile[k0+j][nr]; w1.h[j] = tile[k0+8+j][nr]; }
    *(uint4*)(D + (size_t)(nb+nr)*K + kb + k0)     = w0.u;
    *(uint4*)(D + (size_t)(nb+nr)*K + kb + k0 + 8) = w1.u;
  }
}
// gw2[t][n] = sum_k g_k W2[k][n];  bw2[t][n] = sum_k b_k W2[k][n] + b2[n]
// block = (64-col chunk, t); 256 thr = 64 cols x 4 k-quarters, LDS reduce.
__global__ __launch_bounds__(256) void colsums_kernel(
    const float* __restrict__ W2, const float* __restrict__ g, const float* __restrict__ b,
    const float* __restrict__ b2, float* __restrict__ gw2, float* __restrict__ bw2){
  __shared__ float red[2][4][64];
  int t = blockIdx.y;
  int c0 = blockIdx.x*64;
  int cl = threadIdx.x & 63;
  int kq = threadIdx.x >> 6;
  int col = c0 + cl;
  const float* w = W2 + (size_t)t*512*1024;
  float sg = 0.f, sb = 0.f;
  for (int k = kq*128; k < kq*128 + 128; k++){
    float wv = w[(size_t)k*1024 + col];
    sg += g[t*512 + k] * wv;
    sb += b[t*512 + k] * wv;
  }
  red[0][kq][cl] = sg;
  red[1][kq][cl] = sb;
  __syncthreads();
  if (kq == 0){
    sg = red[0][0][cl] + red[0][1][cl] + red[0][2][cl] + red[0][3][cl];
    sb = red[1][0][cl] + red[1][1][cl] + red[1][2][cl] + red[1][3][cl];
    gw2[t*1024 + col] = sg;
    bw2[t*1024 + col] = sb + b2[t*1024 + col];
  }
}

/* ---------------- feat: per-edge bilinear overlaps (fp32 in, bf16 out) -------
   Wave-synchronous: LDS region is wave-private, so NO __syncthreads — cross-lane
   LDS exchange is ordered by s_waitcnt lgkmcnt(0) (wave lockstep). All 6 global
   loads (12 dwordx4) issued up front so em rides the same latency window as the
   staging loads. */
__global__ __launch_bounds__(256) void feat_kernel(
    const float* __restrict__ x, const int* __restrict__ eidx,
    const float* __restrict__ efa, const float* __restrict__ efb,
    const float* __restrict__ em, const int* __restrict__ order,
    u16* __restrict__ feat){
  __shared__ __align__(16) u16 sm[4*2048];
  const int tid = threadIdx.x;
  const int w = tid >> 6, lane = tid & 63;
  const int q = lane >> 4, ln = lane & 15;
  u16* wb = sm + w*2048;
  u16* AT = wb;         // efa^T (16x32)
  u16* XT = wb + 512;   // xa^T
  u16* B1 = wb + 1024;  // efb^T -> P^T
  u16* B2 = wb + 1536;  // xb^T  -> Q^T

  int p = blockIdx.x*4 + w;
  int e = order[p];
  bool valid = (e >= 0);
  int e0 = valid ? e : 0;
  int ns = eidx[e0];
  int nd = eidx[EDGES + e0];

  // issue ALL global loads up front (independent, max outstanding)
  float va[8], vb[8], vm0[8], vm1[8], vx[8], vd[8];
  load8f(efa + (size_t)e0*512 + lane*8, va);
  load8f(efb + (size_t)e0*512 + lane*8, vb);
  load8f(em  + (size_t)e0*1024 + ln*32 + q*8, vm0);
  load8f(em  + (size_t)e0*1024 + (16+ln)*32 + q*8, vm1);
  load8f(x   + (size_t)ns*512 + lane*8, vx);
  load8f(x   + (size_t)nd*512 + lane*8, vd);

  { // transpose-stage the four (32,16) matrices, converting fp32->bf16
    int i = lane >> 1, cb = (lane & 1) * 8;
    #pragma unroll
    for (int j = 0; j < 8; j++){
      int a = tadr(cb + j, i);
      AT[a] = f2b(va[j]); XT[a] = f2b(vx[j]);
      B1[a] = f2b(vb[j]); B2[a] = f2b(vd[j]);
    }
  }
  WAVE_LDS_FENCE();        // all lanes' staging writes visible to the wave

  bf16x8 mtop = pack8(vm0);
  bf16x8 mbot = pack8(vm1);
  int fb = tadr(ln, q*8);
  bf16x8 bfr = *(const bf16x8*)(B1 + fb);
  bf16x8 xbr = *(const bf16x8*)(B2 + fb);
  f32x4 z4 = {0.f,0.f,0.f,0.f};
  f32x4 Pt = MFMA16(mtop, bfr, z4);
  f32x4 Pb = MFMA16(mbot, bfr, z4);
  f32x4 Qt = MFMA16(mtop, xbr, z4);
  f32x4 Qb = MFMA16(mbot, xbr, z4);

  { // write P^T, Q^T (bf16) back; C/D: col=ln, row=4q+r
    // (DS pipe is in-order per wave: these writes cannot pass the reads above)
    union{ushort4 v; u16 h[4];} t0;
    int a0 = tadr(ln, 4*q), a1 = tadr(ln, 16 + 4*q);
    t0.h[0]=f2b(Pt[0]); t0.h[1]=f2b(Pt[1]); t0.h[2]=f2b(Pt[2]); t0.h[3]=f2b(Pt[3]);
    *(ushort4*)(B1 + a0) = t0.v;
    t0.h[0]=f2b(Pb[0]); t0.h[1]=f2b(Pb[1]); t0.h[2]=f2b(Pb[2]); t0.h[3]=f2b(Pb[3]);
    *(ushort4*)(B1 + a1) = t0.v;
    t0.h[0]=f2b(Qt[0]); t0.h[1]=f2b(Qt[1]); t0.h[2]=f2b(Qt[2]); t0.h[3]=f2b(Qt[3]);
    *(ushort4*)(B2 + a0) = t0.v;
    t0.h[0]=f2b(Qb[0]); t0.h[1]=f2b(Qb[1]); t0.h[2]=f2b(Qb[2]); t0.h[3]=f2b(Qb[3]);
    *(ushort4*)(B2 + a1) = t0.v;
  }
  WAVE_LDS_FENCE();        // P^T/Q^T visible

  bf16x8 atf = *(const bf16x8*)(AT + fb);
  bf16x8 xaf = *(const bf16x8*)(XT + fb);
  bf16x8 ptf = *(const bf16x8*)(B1 + fb);
  bf16x8 qtf = *(const bf16x8*)(B2 + fb);
  f32x4 Oe = MFMA16(atf, ptf, z4);
  f32x4 On = MFMA16(xaf, qtf, z4);
  if (valid){
    u16* fp = feat + (size_t)p*512;
    #pragma unroll
    for (int r = 0; r < 4; r++){
      fp[(4*q+r)*16 + ln]       = f2b(Oe[r]);
      fp[256 + (4*q+r)*16 + ln] = f2b(On[r]);
    }
  }
}

/* ---------------- GEMM (128x128xK512, BK=64), typed by row segment ----------------
   m97 structure: single-buffer LDS slabs filled by global_load_lds_dwordx4
   (async, no VGPR round-trip), 2 barriers per K-step; cross-block TLP
   (3-4 blocks/CU) covers the load latency. LDS layout linear; the XOR chunk
   swizzle (chunk c of row r at slot c^(r&7)) is applied by pre-swizzling the
   per-lane GLOBAL source address (rule 21), ds_read uses the same XOR.
   Bijective XCD remap (n-fastest) keeps an m-tile's n-blocks on one XCD.
   EPI 0: C = silu(A@B + b1[t]) -> h bf16; fused LN partial sums via atomics.
   EPI 1: finalize mean/rsig; C = rs*(A@B) + bw2 - rs*mu*gw2, guarded stores. */
template<int EPI>
__global__ __launch_bounds__(256,3) void gemm_epi(
    const u16* __restrict__ A, const u16* __restrict__ Ball, int N,
    const int* __restrict__ pad_off, const float* __restrict__ bias,
    float* __restrict__ mu, float* __restrict__ rsig,
    const float* __restrict__ gw2, const float* __restrict__ bw2,
    u16* __restrict__ C, const int* __restrict__ order){
  // ---- XCD swizzle (bijective): lin%8 = XCD under round-robin dispatch
  const int NX = gridDim.x;
  const int NB = NX * (int)gridDim.y;
  int lin = blockIdx.y * NX + blockIdx.x;
  int xcd = lin & 7, idx = lin >> 3;
  int qq = NB >> 3, r8 = NB & 7;
  int base = (xcd < r8) ? xcd * (qq + 1) : r8 * (qq + 1) + (xcd - r8) * qq;
  int work = base + idx;
  int by = work / NX;
  int bx = work - by * NX;

  int m0 = by * 128;
  int total = pad_off[4];
  if (m0 >= total) return;
  int t = 0;
  while (m0 >= pad_off[t+1]) t++;
  int n0 = bx * 128;
  const u16* BT = Ball + (size_t)t * N * 512;   // (N,512) bf16 row-major

  __shared__ __align__(16) u16 smem[128*136];   // 34816B; K-loop uses first 32KB
  u16* smA = smem;                               // slab: 128 rows x 64 k (16KB)
  u16* smB = smem + 128*64;

  const int tid = threadIdx.x;
  const int lane = tid & 63;
  const int w = tid >> 6;
  const int q = lane >> 4, ln = lane & 15;
  const int wm = w >> 1, wn = w & 1;

  f32x4 z4 = {0.f,0.f,0.f,0.f};
  f32x4 acc[4][4];
  #pragma unroll
  for (int mt=0;mt<4;mt++)
    #pragma unroll
    for (int nt=0;nt<4;nt++) acc[mt][nt] = z4;

  // staging map: lane l of wave w, instr j fills row = w*32+j*8+(l>>3),
  // chunk (l&7); global chunk = (l&7) ^ (row&7) = (l&7) ^ (l>>3).
  const int srow = w*32 + (lane >> 3);
  const int gch  = ((lane & 7) ^ (lane >> 3)) * 8;   // u16 elements
  const u16* Agl = A  + (size_t)(m0 + srow)*512 + gch;
  const u16* Bgl = BT + (size_t)(n0 + srow)*512 + gch;
  u16* ldsA = smA + w*2048;    // uniform per wave; +j*512 per instr
  u16* ldsB = smB + w*2048;

  for (int kc = 0; kc < 512; kc += 64){
    __syncthreads();           // prev K-step's ds_reads done; slab reusable
    #pragma unroll
    for (int j = 0; j < 4; j++){
      gl16(Agl + (size_t)j*4096 + kc, ldsA + j*512);
      gl16(Bgl + (size_t)j*4096 + kc, ldsB + j*512);
    }
    __syncthreads();           // compiler drains vmcnt(0) before barrier
    #pragma unroll
    for (int ks = 0; ks < 2; ks++){
      bf16x8 af[4], bfr[4];
      #pragma unroll
      for (int mt = 0; mt < 4; mt++){
        int row = wm*64 + mt*16 + ln;
        int ch = (ks*4 + q) ^ (row & 7);
        af[mt] = *(const bf16x8*)(smA + row*64 + ch*8);
      }
      #pragma unroll
      for (int nt = 0; nt < 4; nt++){
        int row = wn*64 + nt*16 + ln;
        int ch = (ks*4 + q) ^ (row & 7);
        bfr[nt] = *(const bf16x8*)(smB + row*64 + ch*8);
      }
      // swapped operands: D[n=(q,reg)][m=ln] (lane owns 4 consecutive C-columns)
      #pragma unroll
      for (int mt = 0; mt < 4; mt++)
        #pragma unroll
        for (int nt = 0; nt < 4; nt++)
          acc[mt][nt] = MFMA16(bfr[nt], af[mt], acc[mt][nt]);
    }
  }

  __syncthreads();            // all waves done reading smA/smB
  u16* cs = smem;             // 128x136 u16 C-stage (row-major local tile)

  if (EPI == 0){
    const float* bb = bias + (size_t)t * N;
    #pragma unroll
    for (int mt = 0; mt < 4; mt++){
      int ml = wm*64 + mt*16 + ln;       // local C row
      #pragma unroll
      for (int nt = 0; nt < 4; nt++){
        int nl = wn*64 + nt*16 + q*4;    // local C col (4 consecutive)
        union{ushort4 v; u16 h[4];} pk;
        #pragma unroll
        for (int r2 = 0; r2 < 4; r2++){
          float vv = acc[mt][nt][r2] + bb[n0 + nl + r2];
          pk.h[r2] = f2b(vv / (1.f + __expf(-vv)));
        }
        *(ushort4*)(cs + ml*136 + nl) = pk.v;
      }
    }
  } else {
    const float* g2 = gw2 + (size_t)t * N;
    const float* bw = bw2 + (size_t)t * N;
    #pragma unroll
    for (int mt = 0; mt < 4; mt++){
      int ml = wm*64 + mt*16 + ln;
      int row = m0 + ml;
      float s  = mu[row], s2 = rsig[row];      // raw sums from gemm0
      float mean = s * (1.f/512.f);
      float var  = fmaxf(s2 * (1.f/512.f) - mean*mean, 0.f);
      float rs = rsqrtf(var + 1e-5f);
      #pragma unroll
      for (int nt = 0; nt < 4; nt++){
        int nl = wn*64 + nt*16 + q*4;
        union{ushort4 v; u16 h[4];} pk;
        #pragma unroll
        for (int r2 = 0; r2 < 4; r2++){
          int col = n0 + nl + r2;
          pk.h[r2] = f2b(rs*acc[mt][nt][r2] + bw[col] - rs*mean*g2[col]);
        }
        *(ushort4*)(cs + ml*136 + nl) = pk.v;
      }
    }
  }
  __syncthreads();

  // coalesced stores: 16 rows/pass, 16 lanes x 16B = 256B contiguous per row.
  // EPI==0 additionally folds the LN partial sums (quarter-wave reduce + atomic).
  #pragma unroll
  for (int ps = 0; ps < 8; ps++){
    int rl = ps*16 + (tid >> 4);
    int row = m0 + rl;
    union{uint4 v; u16 h[8];} P;
    P.v = *(const uint4*)(cs + rl*136 + (tid & 15)*8);
    if (EPI == 0){
      float s = 0.f, s2 = 0.f;
      #pragma unroll
      for (int j = 0; j < 8; j++){ float v = b2f(P.h[j]); s += v; s2 += v*v; }
      #pragma unroll
      for (int mm = 1; mm < 16; mm <<= 1){
        s += __shfl_xor(s, mm); s2 += __shfl_xor(s2, mm);
      }
      if ((tid & 15) == 0){
        atomicAdd(&mu[row], s);
        atomicAdd(&rsig[row], s2);
      }
      *(uint4*)(C + (size_t)row*N + n0 + (tid & 15)*8) = P.v;
    } else {
      if (order[row] >= 0)
        *(uint4*)(C + (size_t)row*N + n0 + (tid & 15)*8) = P.v;
    }
  }
}

/* ---------------- fro-norm + apply (fp32 in, fp32 out) ----------------
   cbuf is wave-private -> wave-synchronous, no __syncthreads. */
__global__ __launch_bounds__(256) void apply_kernel(
    const float* __restrict__ x, const int* __restrict__ eidx,
    const float* __restrict__ efa, const float* __restrict__ efb,
    const u16* __restrict__ wbuf, const int* __restrict__ order,
    float* __restrict__ out){
  __shared__ __align__(16) u16 sm[4*1024];
  const int tid = threadIdx.x;
  const int w = tid >> 6, lane = tid & 63;
  const int q = lane >> 4, ln = lane & 15;
  u16* cbuf = sm + w*1024;

  int p = blockIdx.x*4 + w;
  int e = order[p];
  bool valid = (e >= 0);
  int e0 = valid ? e : 0;
  size_t p0 = valid ? (size_t)p : 0;
  int ns = eidx[e0], nd = eidx[EDGES + e0];

  const u16* wrow = wbuf + p0*1024;
  union{uint4 v; u16 h[8];} L0, L1;
  L0.v = *(const uint4*)(wrow + lane*16);
  L1.v = *(const uint4*)(wrow + lane*16 + 8);
  float v[16];
  #pragma unroll
  for (int j = 0; j < 8; j++){ v[j] = b2f(L0.h[j]); v[8+j] = b2f(L1.h[j]); }
  float ss = 0.f;
  #pragma unroll
  for (int j = 0; j < 16; j++) ss += v[j]*v[j];
  ss += __shfl_xor(ss, 1); ss += __shfl_xor(ss, 2);
  ss += __shfl_xor(ss, 4); ss += __shfl_xor(ss, 8);
  float scale = 1.f / (sqrtf(ss) + 1e-6f);
  {
    int m = lane >> 4;
    #pragma unroll
    for (int j = 0; j < 16; j++) cbuf[cadr(m, ln, j)] = f2b(v[j]*scale);
  }
  WAVE_LDS_FENCE();

  bf16x8 zb = bzero();
  bf16x8 Fewa=zb, Fewb=zb, Fnwa=zb, Fnwb=zb;
  bf16x8 fat=zb, fab=zb, fbt=zb, fbb=zb, xat=zb, xab=zb, xbt=zb, xbb=zb;
  if (q < 2){
    Fewa = *(const bf16x8*)(cbuf + cadr(0, q*8, ln));
    Fewb = *(const bf16x8*)(cbuf + cadr(1, q*8, ln));
    Fnwa = *(const bf16x8*)(cbuf + cadr(2, q*8, ln));
    Fnwb = *(const bf16x8*)(cbuf + cadr(3, q*8, ln));
    const float* ea = efa + (size_t)e0*512;
    const float* eb = efb + (size_t)e0*512;
    const float* xs = x + (size_t)ns*512;
    const float* xd = x + (size_t)nd*512;
    float t8[8];
    load8f(ea + ln*16 + q*8, t8);      fat = pack8(t8);
    load8f(ea + (16+ln)*16 + q*8, t8); fab = pack8(t8);
    load8f(eb + ln*16 + q*8, t8);      fbt = pack8(t8);
    load8f(eb + (16+ln)*16 + q*8, t8); fbb = pack8(t8);
    load8f(xs + ln*16 + q*8, t8);      xat = pack8(t8);
    load8f(xs + (16+ln)*16 + q*8, t8); xab = pack8(t8);
    load8f(xd + ln*16 + q*8, t8);      xbt = pack8(t8);
    load8f(xd + (16+ln)*16 + q*8, t8); xbb = pack8(t8);
  }
  f32x4 z4 = {0.f,0.f,0.f,0.f};
  f32x4 oat = MFMA16(xat, Fnwa, z4); oat = MFMA16(fat, Fewa, oat);
  f32x4 oab = MFMA16(xab, Fnwa, z4); oab = MFMA16(fab, Fewa, oab);
  f32x4 obt = MFMA16(xbt, Fnwb, z4); obt = MFMA16(fbt, Fewb, obt);
  f32x4 obb = MFMA16(xbb, Fnwb, z4); obb = MFMA16(fbb, Fewb, obb);
  if (valid){
    float* oa = out + (size_t)e0*512;
    float* ob = out + (size_t)EDGES*512 + (size_t)e0*512;
    #pragma unroll
    for (int r = 0; r < 4; r++){
      oa[(4*q+r)*16 + ln]    = 0.5f*oat[r];
      oa[(16+4*q+r)*16 + ln] = 0.5f*oab[r];
      ob[(4*q+r)*16 + ln]    = 0.5f*obt[r];
      ob[(16+4*q+r)*16 + ln] = 0.5f*obb[r];
    }
  }
}

/* ---------------- launch ---------------- */
extern "C" void kernel_launch(void* const* d_in, const int* in_sizes, int n_in,
                              void* d_out, int out_size, void* d_ws, size_t ws_size,
                              hipStream_t stream){
  (void)in_sizes; (void)n_in; (void)out_size; (void)ws_size;
  const float* x   = (const float*)d_in[0];
  const int* eidx  = (const int*)d_in[1];
  const float* efa = (const float*)d_in[2];
  const float* efb = (const float*)d_in[3];
  const float* em  = (const float*)d_in[4];
  const int* an    = (const int*)d_in[5];
  const float* W1  = (const float*)d_in[6];
  const float* b1  = (const float*)d_in[7];
  const float* lng = (const float*)d_in[8];
  const float* lnb = (const float*)d_in[9];
  const float* W2  = (const float*)d_in[10];
  const float* b2  = (const float*)d_in[11];
  float* out = (float*)d_out;

  // scratch plan:
  //   feat (PADMAX x 512 bf16, 34MB)  -> first quarter of d_out (134MB fp32),
  //       dead before apply_kernel overwrites d_out.
  //   h    (PADMAX x 512 bf16, 34MB)  -> edge_matrices[0:34MB]   (em dead after feat)
  //   w    (PADMAX x 1024 bf16, 68MB) -> edge_matrices[34MB:102MB]
  //   ws: small buffers + transposed weights.
  u16* feat = (u16*)d_out;
  u16* em_scratch = (u16*)d_in[4];
  u16* hbuf = em_scratch;
  u16* wbuf = em_scratch + (size_t)PADMAX*512;

  char* ws = (char*)d_ws;
  size_t off = 0;
  int* wsi = (int*)ws;                         off = 256;
  int* order = (int*)(ws + off);               off += (size_t)PADMAX*4;
  float* mu  = (float*)(ws + off);             off += (size_t)PADMAX*4;
  float* rsg = (float*)(ws + off);             off += (size_t)PADMAX*4;
  off = (off + 255) & ~(size_t)255;
  float* gw2 = (float*)(ws + off);             off += (size_t)4*1024*4;
  float* bw2 = (float*)(ws + off);             off += (size_t)4*1024*4;
  u16* W1T   = (u16*)(ws + off);               off += (size_t)4*512*512*2;
  u16* G2T   = (u16*)(ws + off);               off += (size_t)4*512*1024*2;

  hipMemsetAsync(wsi, 0, 64, stream);
  hipMemsetAsync(order, 0xFF, (size_t)PADMAX*4, stream);
  hipMemsetAsync(mu, 0, (size_t)PADMAX*8, stream);   // zero mu+rsg (LN sum/sumsq)

  count_kernel  <<<EDGES/256, 256, 0, stream>>>(eidx, an, wsi);
  scan_kernel   <<<1, 64, 0, stream>>>(wsi);
  scatter_kernel<<<EDGES/256, 256, 0, stream>>>(eidx, an, wsi, order);

  transpose_scale<<<dim3(8,8,4),  256, 0, stream>>>(W1, W1T, nullptr, 512, 512);
  transpose_scale<<<dim3(16,8,4), 256, 0, stream>>>(W2, G2T, lng, 512, 1024);
  colsums_kernel <<<dim3(16,4),   256, 0, stream>>>(W2, lng, lnb, b2, gw2, bw2);

  feat_kernel<<<PADMAX/4, 256, 0, stream>>>(x, eidx, efa, efb, em, order, feat);

  gemm_epi<0><<<dim3(4, MTILES), 256, 0, stream>>>(
      feat, W1T, 512, wsi+8, b1, mu, rsg, nullptr, nullptr,
      hbuf, order);

  gemm_epi<1><<<dim3(8, MTILES), 256, 0, stream>>>(
      hbuf, G2T, 1024, wsi+8, nullptr, mu, rsg, gw2, bw2,
      wbuf, order);

  apply_kernel<<<PADMAX/4, 256, 0, stream>>>(x, eidx, efa, efb, wbuf, order, out);
}

// Round 6
// 578.851 us; speedup vs baseline: 1.0317x; 1.0317x over previous
//
#include <hip/hip_runtime.h>

#define EDGES 32768
#define NODES 8192
#define PADMAX (EDGES + 4*128)   /* 33280: type segments padded to 128 rows */
#define MTILES (PADMAX/128)      /* 260 */

typedef unsigned short u16;
typedef __bf16 bf16x8 __attribute__((ext_vector_type(8)));
typedef float f32x4 __attribute__((ext_vector_type(4)));

#define MFMA16(a,b,c) __builtin_amdgcn_mfma_f32_16x16x32_bf16(a,b,c,0,0,0)
#define WAVE_LDS_FENCE() asm volatile("s_waitcnt lgkmcnt(0)" ::: "memory")

typedef __attribute__((address_space(1))) const unsigned int gas_u32;
typedef __attribute__((address_space(3))) unsigned int las_u32;
__device__ __forceinline__ void gl16(const void* g, void* l){
  __builtin_amdgcn_global_load_lds((gas_u32*)g, (las_u32*)l, 16, 0, 0);
}

__device__ __forceinline__ float b2f(u16 u){
  union{unsigned i; float f;} x; x.i = ((unsigned)u)<<16; return x.f;
}
__device__ __forceinline__ u16 f2b(float f){
  union{float f; unsigned i;} x; x.f = f;
  return (u16)((x.i + 0x7FFFu + ((x.i>>16)&1u)) >> 16);
}
__device__ __forceinline__ bf16x8 bzero(){
  bf16x8 z;
  #pragma unroll
  for (int i=0;i<8;i++) z[i] = (__bf16)0.0f;
  return z;
}
__device__ __forceinline__ void load8f(const float* p, float* v){
  *(float4*)(v)   = *(const float4*)(p);
  *(float4*)(v+4) = *(const float4*)(p+4);
}
__device__ __forceinline__ bf16x8 pack8(const float* v){
  bf16x8 r;
  #pragma unroll
  for (int j=0;j<8;j++) r[j] = (__bf16)v[j];
  return r;
}
// 16x32 bf16 LDS buffer, XOR-swizzled 8-elem chunks.
__device__ __forceinline__ int tadr(int c, int i){
  return c*32 + ((((i>>3) ^ ((c>>1)&3))&3)<<3) + (i&7);
}
// 4 chunk matrices (16x16 each)
__device__ __forceinline__ int cadr(int m, int cpr, int cc){
  return cc*64 + ((((m<<1) | (cpr>>3)) ^ (cc&7))<<3) + (cpr&7);
}

/* ---------------- sort by type (wave-aggregated atomics, G12) ---------------- */
__global__ void count_kernel(const int* __restrict__ eidx, const int* __restrict__ an,
                             int* __restrict__ wsi){
  int e = blockIdx.x*256 + threadIdx.x;
  int lane = threadIdx.x & 63;
  int t = an[eidx[e]] & 3;
  #pragma unroll
  for (int k = 0; k < 4; k++){
    unsigned long long m = __ballot(t == k);
    if (lane == k && m)
      atomicAdd(&wsi[k], __popcll(m));
  }
}
__global__ void scan_kernel(int* wsi){
  if (threadIdx.x == 0 && blockIdx.x == 0){
    int off = 0;
    for (int t = 0; t < 4; t++){
      wsi[8+t] = off;      // pad_off[t]
      wsi[4+t] = off;      // cursor[t]
      off += ((wsi[t] + 127) >> 7) << 7;
    }
    wsi[12] = off;         // pad_off[4] = total padded rows
  }
}
// order[pos] = e  (padded slot -> edge), inv[e] = pos (edge -> padded slot)
__global__ void scatter_kernel(const int* __restrict__ eidx, const int* __restrict__ an,
                               int* wsi, int* __restrict__ order, int* __restrict__ inv){
  int e = blockIdx.x*256 + threadIdx.x;
  int lane = threadIdx.x & 63;
  int t = an[eidx[e]] & 3;
  unsigned long long lt = (1ull << lane) - 1ull;
  int pos = 0;
  #pragma unroll
  for (int k = 0; k < 4; k++){
    unsigned long long m = __ballot(t == k);      // convergent
    int bb = 0;
    if (lane == k && m) bb = atomicAdd(&wsi[4+k], __popcll(m));
    bb = __shfl(bb, k);                           // convergent broadcast
    if (t == k) pos = bb + __popcll(m & lt);
  }
  order[pos] = e;
  inv[e] = pos;
}

/* ---------------- weight prep: fp32 (K,N) -> bf16 (N,K), optional row scale --- */
__global__ __launch_bounds__(256) void transpose_scale(
    const float* __restrict__ src, u16* __restrict__ dst, const float* __restrict__ gvec,
    int K, int Ncols){
  __shared__ u16 tile[64][65];
  int t = blockIdx.z;
  const float* S = src + (size_t)t*K*Ncols;
  u16* D = dst + (size_t)t*K*Ncols;
  int kb = blockIdx.y*64, nb = blockIdx.x*64;
  int tid = threadIdx.x;
  {
    int rr = tid >> 2, c0 = (tid & 3)*16;
    float g = gvec ? gvec[t*K + kb + rr] : 1.f;
    float v[16];
    load8f(S + (size_t)(kb+rr)*Ncols + nb + c0,     v);
    load8f(S + (size_t)(kb+rr)*Ncols + nb + c0 + 8, v+8);
    #pragma unroll
    for (int j=0;j<16;j++) tile[rr][c0+j] = f2b(v[j]*g);
  }
  __syncthreads();
  {
    int nr = tid >> 2, k0 = (tid & 3)*16;
    union{uint4 u; u16 h[8];} w0, w1;
    #pragma unroll
    for (int j=0;j<8;j++){ w0.h[j] = tile[k0+j][nr]; w1.h[j] = tile[k0+8+j][nr]; }
    *(uint4*)(D + (size_t)(nb+nr)*K + kb + k0)     = w0.u;
    *(uint4*)(D + (size_t)(nb+nr)*K + kb + k0 + 8) = w1.u;
  }
}
// gw2[t][n] = sum_k g_k W2[k][n];  bw2[t][n] = sum_k b_k W2[k][n] + b2[n]
__global__ __launch_bounds__(256) void colsums_kernel(
    const float* __restrict__ W2, const float* __restrict__ g, const float* __restrict__ b,
    const float* __restrict__ b2, float* __restrict__ gw2, float* __restrict__ bw2){
  __shared__ float red[2][4][64];
  int t = blockIdx.y;
  int c0 = blockIdx.x*64;
  int cl = threadIdx.x & 63;
  int kq = threadIdx.x >> 6;
  int col = c0 + cl;
  const float* w = W2 + (size_t)t*512*1024;
  float sg = 0.f, sb = 0.f;
  for (int k = kq*128; k < kq*128 + 128; k++){
    float wv = w[(size_t)k*1024 + col];
    sg += g[t*512 + k] * wv;
    sb += b[t*512 + k] * wv;
  }
  red[0][kq][cl] = sg;
  red[1][kq][cl] = sb;
  __syncthreads();
  if (kq == 0){
    sg = red[0][0][cl] + red[0][1][cl] + red[0][2][cl] + red[0][3][cl];
    sb = red[1][0][cl] + red[1][1][cl] + red[1][2][cl] + red[1][3][cl];
    gw2[t*1024 + col] = sg;
    bw2[t*1024 + col] = sb + b2[t*1024 + col];
  }
}

/* ---------------- feat: per-edge bilinear overlaps (fp32 in, bf16 out) -------
   NATURAL edge order: em/efa/efb stream sequentially (full HBM BW); the type
   permutation is paid later by gemm0's per-lane gather staging. Wave-sync
   (LDS region wave-private), all global loads issued up front. */
__global__ __launch_bounds__(256) void feat_kernel(
    const float* __restrict__ x, const int* __restrict__ eidx,
    const float* __restrict__ efa, const float* __restrict__ efb,
    const float* __restrict__ em,
    u16* __restrict__ feat){
  __shared__ __align__(16) u16 sm[4*2048];
  const int tid = threadIdx.x;
  const int w = tid >> 6, lane = tid & 63;
  const int q = lane >> 4, ln = lane & 15;
  u16* wb = sm + w*2048;
  u16* AT = wb;         // efa^T (16x32)
  u16* XT = wb + 512;   // xa^T
  u16* B1 = wb + 1024;  // efb^T -> P^T
  u16* B2 = wb + 1536;  // xb^T  -> Q^T

  int e0 = blockIdx.x*4 + w;
  int ns = eidx[e0];
  int nd = eidx[EDGES + e0];

  // issue ALL global loads up front (independent, max outstanding)
  float va[8], vb[8], vm0[8], vm1[8], vx[8], vd[8];
  load8f(efa + (size_t)e0*512 + lane*8, va);
  load8f(efb + (size_t)e0*512 + lane*8, vb);
  load8f(em  + (size_t)e0*1024 + ln*32 + q*8, vm0);
  load8f(em  + (size_t)e0*1024 + (16+ln)*32 + q*8, vm1);
  load8f(x   + (size_t)ns*512 + lane*8, vx);
  load8f(x   + (size_t)nd*512 + lane*8, vd);

  { // transpose-stage the four (32,16) matrices, converting fp32->bf16
    int i = lane >> 1, cb = (lane & 1) * 8;
    #pragma unroll
    for (int j = 0; j < 8; j++){
      int a = tadr(cb + j, i);
      AT[a] = f2b(va[j]); XT[a] = f2b(vx[j]);
      B1[a] = f2b(vb[j]); B2[a] = f2b(vd[j]);
    }
  }
  WAVE_LDS_FENCE();        // all lanes' staging writes visible to the wave

  bf16x8 mtop = pack8(vm0);
  bf16x8 mbot = pack8(vm1);
  int fb = tadr(ln, q*8);
  bf16x8 bfr = *(const bf16x8*)(B1 + fb);
  bf16x8 xbr = *(const bf16x8*)(B2 + fb);
  f32x4 z4 = {0.f,0.f,0.f,0.f};
  f32x4 Pt = MFMA16(mtop, bfr, z4);
  f32x4 Pb = MFMA16(mbot, bfr, z4);
  f32x4 Qt = MFMA16(mtop, xbr, z4);
  f32x4 Qb = MFMA16(mbot, xbr, z4);

  { // write P^T, Q^T (bf16) back; C/D: col=ln, row=4q+r
    union{ushort4 v; u16 h[4];} t0;
    int a0 = tadr(ln, 4*q), a1 = tadr(ln, 16 + 4*q);
    t0.h[0]=f2b(Pt[0]); t0.h[1]=f2b(Pt[1]); t0.h[2]=f2b(Pt[2]); t0.h[3]=f2b(Pt[3]);
    *(ushort4*)(B1 + a0) = t0.v;
    t0.h[0]=f2b(Pb[0]); t0.h[1]=f2b(Pb[1]); t0.h[2]=f2b(Pb[2]); t0.h[3]=f2b(Pb[3]);
    *(ushort4*)(B1 + a1) = t0.v;
    t0.h[0]=f2b(Qt[0]); t0.h[1]=f2b(Qt[1]); t0.h[2]=f2b(Qt[2]); t0.h[3]=f2b(Qt[3]);
    *(ushort4*)(B2 + a0) = t0.v;
    t0.h[0]=f2b(Qb[0]); t0.h[1]=f2b(Qb[1]); t0.h[2]=f2b(Qb[2]); t0.h[3]=f2b(Qb[3]);
    *(ushort4*)(B2 + a1) = t0.v;
  }
  WAVE_LDS_FENCE();        // P^T/Q^T visible

  bf16x8 atf = *(const bf16x8*)(AT + fb);
  bf16x8 xaf = *(const bf16x8*)(XT + fb);
  bf16x8 ptf = *(const bf16x8*)(B1 + fb);
  bf16x8 qtf = *(const bf16x8*)(B2 + fb);
  f32x4 Oe = MFMA16(atf, ptf, z4);
  f32x4 On = MFMA16(xaf, qtf, z4);
  {
    u16* fp = feat + (size_t)e0*512;
    #pragma unroll
    for (int r = 0; r < 4; r++){
      fp[(4*q+r)*16 + ln]       = f2b(Oe[r]);
      fp[256 + (4*q+r)*16 + ln] = f2b(On[r]);
    }
  }
}

/* ---------------- GEMM (128x128xK512, BK=64), typed by row segment ----------------
   m97 structure (round-3): global_load_lds slabs, 2 barriers/K-step, 3 blocks/CU.
   EPI 0: A rows GATHERED per lane via order[] (feat stored in natural edge order);
          C = silu(A@B + b1[t]) -> h bf16 (padded order); fused LN sums (atomics).
   EPI 1: A = h, linear padded rows; finalize mean/rsig;
          C = rs*(A@B) + bw2 - rs*mu*gw2, guarded stores. */
template<int EPI>
__global__ __launch_bounds__(256,3) void gemm_epi(
    const u16* __restrict__ A, const u16* __restrict__ Ball, int N,
    const int* __restrict__ pad_off, const float* __restrict__ bias,
    float* __restrict__ mu, float* __restrict__ rsig,
    const float* __restrict__ gw2, const float* __restrict__ bw2,
    u16* __restrict__ C, const int* __restrict__ order){
  // ---- XCD swizzle (bijective): lin%8 = XCD under round-robin dispatch
  const int NX = gridDim.x;
  const int NB = NX * (int)gridDim.y;
  int lin = blockIdx.y * NX + blockIdx.x;
  int xcd = lin & 7, idx = lin >> 3;
  int qq = NB >> 3, r8 = NB & 7;
  int base = (xcd < r8) ? xcd * (qq + 1) : r8 * (qq + 1) + (xcd - r8) * qq;
  int work = base + idx;
  int by = work / NX;
  int bx = work - by * NX;

  int m0 = by * 128;
  int total = pad_off[4];
  if (m0 >= total) return;
  int t = 0;
  while (m0 >= pad_off[t+1]) t++;
  int n0 = bx * 128;
  const u16* BT = Ball + (size_t)t * N * 512;   // (N,512) bf16 row-major

  __shared__ __align__(16) u16 smem[128*136];   // 34816B; K-loop uses first 32KB
  u16* smA = smem;                               // slab: 128 rows x 64 k (16KB)
  u16* smB = smem + 128*64;

  const int tid = threadIdx.x;
  const int lane = tid & 63;
  const int w = tid >> 6;
  const int q = lane >> 4, ln = lane & 15;
  const int wm = w >> 1, wn = w & 1;

  f32x4 z4 = {0.f,0.f,0.f,0.f};
  f32x4 acc[4][4];
  #pragma unroll
  for (int mt=0;mt<4;mt++)
    #pragma unroll
    for (int nt=0;nt<4;nt++) acc[mt][nt] = z4;

  // staging map: lane l of wave w, instr j fills row = w*32+j*8+(l>>3),
  // chunk (l&7); global chunk = (l&7) ^ (row&7) = (l&7) ^ (l>>3).
  const int srow8 = lane >> 3;
  const int gch  = ((lane & 7) ^ srow8) * 8;   // u16 elements
  const u16* AgJ[4];
  #pragma unroll
  for (int j = 0; j < 4; j++){
    int pr = m0 + w*32 + j*8 + srow8;
    if (EPI == 0){
      int oe = order[pr];                      // gather: padded slot -> edge row
      AgJ[j] = A + (size_t)(oe >= 0 ? oe : 0)*512 + gch;
    } else {
      AgJ[j] = A + (size_t)pr*512 + gch;
    }
  }
  const u16* Bgl = BT + (size_t)(n0 + w*32 + srow8)*512 + gch;
  u16* ldsA = smA + w*2048;    // uniform per wave; +j*512 per instr
  u16* ldsB = smB + w*2048;

  for (int kc = 0; kc < 512; kc += 64){
    __syncthreads();           // prev K-step's ds_reads done; slab reusable
    #pragma unroll
    for (int j = 0; j < 4; j++){
      gl16(AgJ[j] + kc, ldsA + j*512);
      gl16(Bgl + (size_t)j*4096 + kc, ldsB + j*512);
    }
    __syncthreads();           // compiler drains vmcnt(0) before barrier
    #pragma unroll
    for (int ks = 0; ks < 2; ks++){
      bf16x8 af[4], bfr[4];
      #pragma unroll
      for (int mt = 0; mt < 4; mt++){
        int row = wm*64 + mt*16 + ln;
        int ch = (ks*4 + q) ^ (row & 7);
        af[mt] = *(const bf16x8*)(smA + row*64 + ch*8);
      }
      #pragma unroll
      for (int nt = 0; nt < 4; nt++){
        int row = wn*64 + nt*16 + ln;
        int ch = (ks*4 + q) ^ (row & 7);
        bfr[nt] = *(const bf16x8*)(smB + row*64 + ch*8);
      }
      // swapped operands: D[n=(q,reg)][m=ln] (lane owns 4 consecutive C-columns)
      #pragma unroll
      for (int mt = 0; mt < 4; mt++)
        #pragma unroll
        for (int nt = 0; nt < 4; nt++)
          acc[mt][nt] = MFMA16(bfr[nt], af[mt], acc[mt][nt]);
    }
  }

  __syncthreads();            // all waves done reading smA/smB
  u16* cs = smem;             // 128x136 u16 C-stage (row-major local tile)

  if (EPI == 0){
    const float* bb = bias + (size_t)t * N;
    #pragma unroll
    for (int mt = 0; mt < 4; mt++){
      int ml = wm*64 + mt*16 + ln;       // local C row
      #pragma unroll
      for (int nt = 0; nt < 4; nt++){
        int nl = wn*64 + nt*16 + q*4;    // local C col (4 consecutive)
        union{ushort4 v; u16 h[4];} pk;
        #pragma unroll
        for (int r2 = 0; r2 < 4; r2++){
          float vv = acc[mt][nt][r2] + bb[n0 + nl + r2];
          pk.h[r2] = f2b(vv / (1.f + __expf(-vv)));
        }
        *(ushort4*)(cs + ml*136 + nl) = pk.v;
      }
    }
  } else {
    const float* g2 = gw2 + (size_t)t * N;
    const float* bw = bw2 + (size_t)t * N;
    #pragma unroll
    for (int mt = 0; mt < 4; mt++){
      int ml = wm*64 + mt*16 + ln;
      int row = m0 + ml;
      float s  = mu[row], s2 = rsig[row];      // raw sums from gemm0
      float mean = s * (1.f/512.f);
      float var  = fmaxf(s2 * (1.f/512.f) - mean*mean, 0.f);
      float rs = rsqrtf(var + 1e-5f);
      #pragma unroll
      for (int nt = 0; nt < 4; nt++){
        int nl = wn*64 + nt*16 + q*4;
        union{ushort4 v; u16 h[4];} pk;
        #pragma unroll
        for (int r2 = 0; r2 < 4; r2++){
          int col = n0 + nl + r2;
          pk.h[r2] = f2b(rs*acc[mt][nt][r2] + bw[col] - rs*mean*g2[col]);
        }
        *(ushort4*)(cs + ml*136 + nl) = pk.v;
      }
    }
  }
  __syncthreads();

  // coalesced stores: 16 rows/pass, 16 lanes x 16B = 256B contiguous per row.
  // EPI==0 additionally folds the LN partial sums (quarter-wave reduce + atomic).
  #pragma unroll
  for (int ps = 0; ps < 8; ps++){
    int rl = ps*16 + (tid >> 4);
    int row = m0 + rl;
    union{uint4 v; u16 h[8];} P;
    P.v = *(const uint4*)(cs + rl*136 + (tid & 15)*8);
    if (EPI == 0){
      float s = 0.f, s2 = 0.f;
      #pragma unroll
      for (int j = 0; j < 8; j++){ float v = b2f(P.h[j]); s += v; s2 += v*v; }
      #pragma unroll
      for (int mm = 1; mm < 16; mm <<= 1){
        s += __shfl_xor(s, mm); s2 += __shfl_xor(s2, mm);
      }
      if ((tid & 15) == 0){
        atomicAdd(&mu[row], s);
        atomicAdd(&rsig[row], s2);
      }
      *(uint4*)(C + (size_t)row*N + n0 + (tid & 15)*8) = P.v;
    } else {
      if (order[row] >= 0)
        *(uint4*)(C + (size_t)row*N + n0 + (tid & 15)*8) = P.v;
    }
  }
}

/* ---------------- fro-norm + apply (fp32 in, fp32 out) ----------------
   NATURAL edge order: efa/efb stream, out writes stream; only the w-row
   (1KB) is gathered via inv[e]. cbuf wave-private -> wave-synchronous. */
__global__ __launch_bounds__(256) void apply_kernel(
    const float* __restrict__ x, const int* __restrict__ eidx,
    const float* __restrict__ efa, const float* __restrict__ efb,
    const u16* __restrict__ wbuf, const int* __restrict__ inv,
    float* __restrict__ out){
  __shared__ __align__(16) u16 sm[4*1024];
  const int tid = threadIdx.x;
  const int w = tid >> 6, lane = tid & 63;
  const int q = lane >> 4, ln = lane & 15;
  u16* cbuf = sm + w*1024;

  int e0 = blockIdx.x*4 + w;
  size_t p0 = (size_t)inv[e0];
  int ns = eidx[e0], nd = eidx[EDGES + e0];

  const u16* wrow = wbuf + p0*1024;
  union{uint4 v; u16 h[8];} L0, L1;
  L0.v = *(const uint4*)(wrow + lane*16);
  L1.v = *(const uint4*)(wrow + lane*16 + 8);
  float v[16];
  #pragma unroll
  for (int j = 0; j < 8; j++){ v[j] = b2f(L0.h[j]); v[8+j] = b2f(L1.h[j]); }
  float ss = 0.f;
  #pragma unroll
  for (int j = 0; j < 16; j++) ss += v[j]*v[j];
  ss += __shfl_xor(ss, 1); ss += __shfl_xor(ss, 2);
  ss += __shfl_xor(ss, 4); ss += __shfl_xor(ss, 8);
  float scale = 1.f / (sqrtf(ss) + 1e-6f);
  {
    int m = lane >> 4;
    #pragma unroll
    for (int j = 0; j < 16; j++) cbuf[cadr(m, ln, j)] = f2b(v[j]*scale);
  }
  WAVE_LDS_FENCE();

  bf16x8 zb = bzero();
  bf16x8 Fewa=zb, Fewb=zb, Fnwa=zb, Fnwb=zb;
  bf16x8 fat=zb, fab=zb, fbt=zb, fbb=zb, xat=zb, xab=zb, xbt=zb, xbb=zb;
  if (q < 2){
    Fewa = *(const bf16x8*)(cbuf + cadr(0, q*8, ln));
    Fewb = *(const bf16x8*)(cbuf + cadr(1, q*8, ln));
    Fnwa = *(const bf16x8*)(cbuf + cadr(2, q*8, ln));
    Fnwb = *(const bf16x8*)(cbuf + cadr(3, q*8, ln));
    const float* ea = efa + (size_t)e0*512;
    const float* eb = efb + (size_t)e0*512;
    const float* xs = x + (size_t)ns*512;
    const float* xd = x + (size_t)nd*512;
    float t8[8];
    load8f(ea + ln*16 + q*8, t8);      fat = pack8(t8);
    load8f(ea + (16+ln)*16 + q*8, t8); fab = pack8(t8);
    load8f(eb + ln*16 + q*8, t8);      fbt = pack8(t8);
    load8f(eb + (16+ln)*16 + q*8, t8); fbb = pack8(t8);
    load8f(xs + ln*16 + q*8, t8);      xat = pack8(t8);
    load8f(xs + (16+ln)*16 + q*8, t8); xab = pack8(t8);
    load8f(xd + ln*16 + q*8, t8);      xbt = pack8(t8);
    load8f(xd + (16+ln)*16 + q*8, t8); xbb = pack8(t8);
  }
  f32x4 z4 = {0.f,0.f,0.f,0.f};
  f32x4 oat = MFMA16(xat, Fnwa, z4); oat = MFMA16(fat, Fewa, oat);
  f32x4 oab = MFMA16(xab, Fnwa, z4); oab = MFMA16(fab, Fewa, oab);
  f32x4 obt = MFMA16(xbt, Fnwb, z4); obt = MFMA16(fbt, Fewb, obt);
  f32x4 obb = MFMA16(xbb, Fnwb, z4); obb = MFMA16(fbb, Fewb, obb);
  {
    float* oa = out + (size_t)e0*512;
    float* ob = out + (size_t)EDGES*512 + (size_t)e0*512;
    #pragma unroll
    for (int r = 0; r < 4; r++){
      oa[(4*q+r)*16 + ln]    = 0.5f*oat[r];
      oa[(16+4*q+r)*16 + ln] = 0.5f*oab[r];
      ob[(4*q+r)*16 + ln]    = 0.5f*obt[r];
      ob[(16+4*q+r)*16 + ln] = 0.5f*obb[r];
    }
  }
}

/* ---------------- launch ---------------- */
extern "C" void kernel_launch(void* const* d_in, const int* in_sizes, int n_in,
                              void* d_out, int out_size, void* d_ws, size_t ws_size,
                              hipStream_t stream){
  (void)in_sizes; (void)n_in; (void)out_size; (void)ws_size;
  const float* x   = (const float*)d_in[0];
  const int* eidx  = (const int*)d_in[1];
  const float* efa = (const float*)d_in[2];
  const float* efb = (const float*)d_in[3];
  const float* em  = (const float*)d_in[4];
  const int* an    = (const int*)d_in[5];
  const float* W1  = (const float*)d_in[6];
  const float* b1  = (const float*)d_in[7];
  const float* lng = (const float*)d_in[8];
  const float* lnb = (const float*)d_in[9];
  const float* W2  = (const float*)d_in[10];
  const float* b2  = (const float*)d_in[11];
  float* out = (float*)d_out;

  // scratch plan:
  //   feat (EDGES x 512 bf16, 34MB, NATURAL order) -> first quarter of d_out,
  //       dead before apply_kernel overwrites d_out.
  //   h    (PADMAX x 512 bf16, 34MB)  -> edge_matrices[0:34MB]   (em dead after feat)
  //   w    (PADMAX x 1024 bf16, 68MB) -> edge_matrices[34MB:102MB]
  //   ws: small buffers + transposed weights.
  u16* feat = (u16*)d_out;
  u16* em_scratch = (u16*)d_in[4];
  u16* hbuf = em_scratch;
  u16* wbuf = em_scratch + (size_t)PADMAX*512;

  char* ws = (char*)d_ws;
  size_t off = 0;
  int* wsi = (int*)ws;                         off = 256;
  int* order = (int*)(ws + off);               off += (size_t)PADMAX*4;
  int* inv   = (int*)(ws + off);               off += (size_t)EDGES*4;
  float* mu  = (float*)(ws + off);             off += (size_t)PADMAX*4;
  float* rsg = (float*)(ws + off);             off += (size_t)PADMAX*4;
  off = (off + 255) & ~(size_t)255;
  float* gw2 = (float*)(ws + off);             off += (size_t)4*1024*4;
  float* bw2 = (float*)(ws + off);             off += (size_t)4*1024*4;
  u16* W1T   = (u16*)(ws + off);               off += (size_t)4*512*512*2;
  u16* G2T   = (u16*)(ws + off);               off += (size_t)4*512*1024*2;

  hipMemsetAsync(wsi, 0, 64, stream);
  hipMemsetAsync(order, 0xFF, (size_t)PADMAX*4, stream);
  hipMemsetAsync(mu, 0, (size_t)PADMAX*8, stream);   // zero mu+rsg (LN sum/sumsq)

  count_kernel  <<<EDGES/256, 256, 0, stream>>>(eidx, an, wsi);
  scan_kernel   <<<1, 64, 0, stream>>>(wsi);
  scatter_kernel<<<EDGES/256, 256, 0, stream>>>(eidx, an, wsi, order, inv);

  transpose_scale<<<dim3(8,8,4),  256, 0, stream>>>(W1, W1T, nullptr, 512, 512);
  transpose_scale<<<dim3(16,8,4), 256, 0, stream>>>(W2, G2T, lng, 512, 1024);
  colsums_kernel <<<dim3(16,4),   256, 0, stream>>>(W2, lng, lnb, b2, gw2, bw2);

  feat_kernel<<<EDGES/4, 256, 0, stream>>>(x, eidx, efa, efb, em, feat);

  gemm_epi<0><<<dim3(4, MTILES), 256, 0, stream>>>(
      feat, W1T, 512, wsi+8, b1, mu, rsg, nullptr, nullptr,
      hbuf, order);

  gemm_epi<1><<<dim3(8, MTILES), 256, 0, stream>>>(
      hbuf, G2T, 1024, wsi+8, nullptr, mu, rsg, gw2, bw2,
      wbuf, order);

  apply_kernel<<<EDGES/4, 256, 0, stream>>>(x, eidx, efa, efb, wbuf, inv, out);
}